// Round 6
// baseline (251.742 us; speedup 1.0000x reference)
//
#include <hip/hip_runtime.h>
#include <math.h>

#define DIM 128
#define NHEADS 16
#define DPH 8
#define NATOMS 50000
#define NEDGES 400000
#define LN_EPS 1e-5f

typedef float f32x4 __attribute__((ext_vector_type(4)));
typedef short s16x8 __attribute__((ext_vector_type(8)));

static __device__ __forceinline__ unsigned short f2bf(float f) {
  unsigned u = __builtin_bit_cast(unsigned, f);
  unsigned r = (u + 0x7FFFu + ((u >> 16) & 1u)) >> 16;  // RNE
  return (unsigned short)r;
}
static __device__ __forceinline__ unsigned packbf(float lo, float hi) {
  return (unsigned)f2bf(lo) | ((unsigned)f2bf(hi) << 16);
}
static __device__ __forceinline__ float bflo(unsigned u) {
  return __builtin_bit_cast(float, u << 16);
}
static __device__ __forceinline__ float bfhi(unsigned u) {
  return __builtin_bit_cast(float, u & 0xffff0000u);
}

// fast GELU (tanh form): x * sigmoid(2*c0*(x + c1*x^3))
static __device__ __forceinline__ float gelu_fast(float x) {
  const float c0 = 0.7978845608028654f;
  const float c1 = 0.044715f;
  float u = c0 * (x + c1 * x * x * x);
  return __fdividef(x, 1.0f + __expf(-2.0f * u));
}

// ---------------------------------------------------------------------------
// Weight convert/transpose: qkv_w [128][384] -> wTq bf16 [384][128];
// out_w [128][128] -> wTo bf16 [128][128] (col-major: wT[c][k]).
// ---------------------------------------------------------------------------
__global__ __launch_bounds__(256) void k_convert_w(
    const float* __restrict__ qkv_w, const float* __restrict__ out_w,
    unsigned short* __restrict__ wTq, unsigned short* __restrict__ wTo)
{
  const int idx = blockIdx.x * 256 + threadIdx.x;
  if (idx < 384 * 128) {
    const int c = idx >> 7, k = idx & 127;
    wTq[idx] = f2bf(qkv_w[k * 384 + c]);
  } else {
    const int i2 = idx - 384 * 128;
    const int c = i2 >> 7, k = i2 & 127;
    wTo[i2] = f2bf(out_w[k * 128 + c]);
  }
}

// ---------------------------------------------------------------------------
// K1: fused LayerNorm + QKV projection (MFMA), LDS-staged coalesced epilogue.
// Block = 256 (4 waves) handles 16 atoms. Wave w -> cols [w*96, w*96+96).
// so[atom][0..127] = q channels (f32), so[atom][128..383] = interleaved {k,v}.
// Final stores pack to bf16: qb u32[a][64] (2 ch/word), kvb u32[a][128]
// ({k,v} packed per channel).
// ---------------------------------------------------------------------------
__global__ __launch_bounds__(256) void k_ln_qkv(
    const float* __restrict__ node, const unsigned short* __restrict__ wTq,
    const float* __restrict__ bias, const float* __restrict__ g,
    const float* __restrict__ beta, unsigned* __restrict__ qb,
    unsigned* __restrict__ kvb)
{
  __shared__ float hpad[16][132];
  __shared__ float so[16][388];
  const int a0 = blockIdx.x * 16;
  const int tid = threadIdx.x;
  const int wid = tid >> 6;
  const int lane = tid & 63;

  // phase 1: LayerNorm (wave `wid` does atoms wid*4 .. +3)
  for (int j = 0; j < 4; ++j) {
    const int a = wid * 4 + j;
    const float x0 = node[(size_t)(a0 + a) * DIM + lane];
    const float x1 = node[(size_t)(a0 + a) * DIM + 64 + lane];
    float s = x0 + x1;
    #pragma unroll
    for (int m = 1; m < 64; m <<= 1) s += __shfl_xor(s, m);
    const float mu = s * (1.0f / 128.0f);
    const float d0 = x0 - mu, d1 = x1 - mu;
    float v = d0 * d0 + d1 * d1;
    #pragma unroll
    for (int m = 1; m < 64; m <<= 1) v += __shfl_xor(v, m);
    const float rs = rsqrtf(v * (1.0f / 128.0f) + LN_EPS);
    hpad[a][lane]      = d0 * rs * g[lane]      + beta[lane];
    hpad[a][64 + lane] = d1 * rs * g[64 + lane] + beta[64 + lane];
  }
  __syncthreads();

  // phase 2: MFMA
  const int lrow = lane & 15;
  const int lquad = lane >> 4;
  const int colbase = wid * 96;

  s16x8 afrag[4];
  #pragma unroll
  for (int ks = 0; ks < 4; ++ks) {
    const int koff = ks * 32 + lquad * 8;
    const float4 p0 = *reinterpret_cast<const float4*>(&hpad[lrow][koff]);
    const float4 p1 = *reinterpret_cast<const float4*>(&hpad[lrow][koff + 4]);
    s16x8 af;
    af[0] = (short)f2bf(p0.x); af[1] = (short)f2bf(p0.y);
    af[2] = (short)f2bf(p0.z); af[3] = (short)f2bf(p0.w);
    af[4] = (short)f2bf(p1.x); af[5] = (short)f2bf(p1.y);
    af[6] = (short)f2bf(p1.z); af[7] = (short)f2bf(p1.w);
    afrag[ks] = af;
  }

  f32x4 acc[6];
  #pragma unroll
  for (int t = 0; t < 6; ++t) acc[t] = (f32x4){0.f, 0.f, 0.f, 0.f};

  #pragma unroll
  for (int t = 0; t < 6; ++t) {
    const int cg = colbase + t * 16 + lrow;
    #pragma unroll
    for (int ks = 0; ks < 4; ++ks) {
      const s16x8 bf = *reinterpret_cast<const s16x8*>(
          &wTq[(size_t)cg * 128 + ks * 32 + lquad * 8]);
      acc[t] = __builtin_amdgcn_mfma_f32_16x16x32_bf16(afrag[ks], bf, acc[t], 0, 0, 0);
    }
  }

  // epilogue: stage into LDS in the q/kv split layout
  #pragma unroll
  for (int t = 0; t < 6; ++t) {
    const int cg = colbase + t * 16 + lrow;
    const float bz = bias[cg];
    const int hj = cg / 24;
    const int off = cg - hj * 24;
    int moff;
    if (off < 8)       moff = hj * 8 + off;                 // q
    else if (off < 16) moff = 128 + (hj * 8 + off - 8) * 2; // k
    else               moff = 128 + (hj * 8 + off - 16) * 2 + 1; // v
    #pragma unroll
    for (int r = 0; r < 4; ++r)
      so[lquad * 4 + r][moff] = acc[t][r] + bz;
  }
  __syncthreads();

  // packed bf16 stores: q = 1024 u32, kv = 2048 u32 per block
  #pragma unroll
  for (int kk = 0; kk < 4; ++kk) {
    const int i = tid + kk * 256;      // 0..1023
    const int rowi = i >> 6;
    const int c2 = i & 63;
    qb[(size_t)(a0 + rowi) * 64 + c2] =
        packbf(so[rowi][2 * c2], so[rowi][2 * c2 + 1]);
  }
  #pragma unroll
  for (int kk = 0; kk < 8; ++kk) {
    const int i = tid + kk * 256;      // 0..2047
    const int rowi = i >> 7;
    const int c = i & 127;
    kvb[(size_t)(a0 + rowi) * 128 + c] =
        packbf(so[rowi][128 + 2 * c], so[rowi][128 + 2 * c + 1]);
  }
}

// ---------------------------------------------------------------------------
// CSR build: histogram -> parallel 3-phase scan -> scatter edge descriptors
// ---------------------------------------------------------------------------
__global__ __launch_bounds__(256) void k_hist(const int* __restrict__ row,
                                              int* __restrict__ cnt) {
  const int e = blockIdx.x * 256 + threadIdx.x;
  if (e < NEDGES) atomicAdd(&cnt[row[e]], 1);
}

#define SCAN_NB 196  // ceil(50000/256)

__global__ __launch_bounds__(256) void k_scan1(const int* __restrict__ cnt,
                                               int* __restrict__ locx,
                                               int* __restrict__ psum) {
  __shared__ int sh[256];
  const int tid = threadIdx.x;
  const int i = blockIdx.x * 256 + tid;
  const int v = (i < NATOMS) ? cnt[i] : 0;
  sh[tid] = v;
  __syncthreads();
  #pragma unroll
  for (int off = 1; off < 256; off <<= 1) {
    const int cur = sh[tid];
    const int add = (tid >= off) ? sh[tid - off] : 0;
    __syncthreads();
    sh[tid] = cur + add;
    __syncthreads();
  }
  if (i < NATOMS) locx[i] = sh[tid] - v;  // exclusive
  if (tid == 255) psum[blockIdx.x] = sh[255];
}

__global__ __launch_bounds__(256) void k_scan2(const int* __restrict__ psum,
                                               int* __restrict__ poff,
                                               int* __restrict__ base) {
  __shared__ int sh[256];
  const int tid = threadIdx.x;
  const int v = (tid < SCAN_NB) ? psum[tid] : 0;
  sh[tid] = v;
  __syncthreads();
  #pragma unroll
  for (int off = 1; off < 256; off <<= 1) {
    const int cur = sh[tid];
    const int add = (tid >= off) ? sh[tid - off] : 0;
    __syncthreads();
    sh[tid] = cur + add;
    __syncthreads();
  }
  if (tid < SCAN_NB) poff[tid] = sh[tid] - v;  // exclusive block offset
  if (tid == 255) base[NATOMS] = sh[255];      // total = NEDGES
}

__global__ __launch_bounds__(256) void k_scan3(const int* __restrict__ locx,
                                               const int* __restrict__ poff,
                                               int* __restrict__ base,
                                               int* __restrict__ cursor) {
  const int i = blockIdx.x * 256 + threadIdx.x;
  if (i < NATOMS) {
    const int b = locx[i] + poff[blockIdx.x];
    base[i] = b;
    cursor[i] = b;
  }
}

// Scatter edge descriptors into CSR order: descA[p]={e,col,radial,ev0},
// descB[p]={ev1,ev2}. Removes all per-edge indirection from the hot loop.
__global__ __launch_bounds__(256) void k_scatter(
    const int* __restrict__ row, const int* __restrict__ col,
    const float* __restrict__ radial, const float* __restrict__ evec,
    int* __restrict__ cursor, int4* __restrict__ descA,
    float2* __restrict__ descB)
{
  const int e = blockIdx.x * 256 + threadIdx.x;
  if (e < NEDGES) {
    const int p = atomicAdd(&cursor[row[e]], 1);
    descA[p] = make_int4(e, col[e], __float_as_int(radial[e]),
                         __float_as_int(evec[(size_t)e * 3]));
    descB[p] = make_float2(evec[(size_t)e * 3 + 1], evec[(size_t)e * 3 + 2]);
  }
}

// ---------------------------------------------------------------------------
// K2: per-atom edge accumulation. 1 wave per atom, 2 channels per lane.
// Descriptors are affine in p (prefetched 2 pairs ahead, no indirection);
// the only dependent level left is desc -> {kv, ef} (1 pair ahead).
// kv is packed bf16 {k,v} per channel: uint2 per lane = 2 channels.
// ---------------------------------------------------------------------------
__global__ __launch_bounds__(256) void k_edge_csr(
    const unsigned* __restrict__ qb, const uint2* __restrict__ kvb,
    const float2* __restrict__ ef2, const int4* __restrict__ descA,
    const float2* __restrict__ descB, const int* __restrict__ base,
    unsigned* __restrict__ mfeatw, float* __restrict__ outvec)
{
  const int tid = threadIdx.x;
  const int a = blockIdx.x * 4 + (tid >> 6);
  const int t = tid & 63;

  const int beg = base[a];
  const int end = base[a + 1];

  float f0 = 0.f, f1 = 0.f;
  float va0 = 0.f, va1 = 0.f, vb0 = 0.f, vb1 = 0.f, vc0 = 0.f, vc1 = 0.f;

  if (beg < end) {
    const unsigned qp = qb[(size_t)a * 64 + t];
    const float q0 = bflo(qp), q1 = bfhi(qp);
    const int last = end - 1;
    auto cidx = [last](int i) { return i <= last ? i : last; };

    int4 nAx, nAy, fAx, fAy;
    float2 nBx, nBy, fBx, fBy;
    uint2 kvx_n, kvy_n;
    float2 efx_n, efy_n;

    // desc pair 0
    nAx = descA[beg];          nBx = descB[beg];
    nAy = descA[cidx(beg + 1)]; nBy = descB[cidx(beg + 1)];
    // data pair 0
    {
      const int cx = __builtin_amdgcn_readfirstlane(nAx.y);
      const int ex = __builtin_amdgcn_readfirstlane(nAx.x);
      const int cy = __builtin_amdgcn_readfirstlane(nAy.y);
      const int ey = __builtin_amdgcn_readfirstlane(nAy.x);
      kvx_n = kvb[(size_t)cx * 64 + t];
      kvy_n = kvb[(size_t)cy * 64 + t];
      efx_n = ef2[(size_t)ex * 64 + t];
      efy_n = ef2[(size_t)ey * 64 + t];
    }
    // desc pair 1
    fAx = descA[cidx(beg + 2)]; fBx = descB[cidx(beg + 2)];
    fAy = descA[cidx(beg + 3)]; fBy = descB[cidx(beg + 3)];

    for (int i = beg; i < end; i += 2) {
      // promote inflight -> compute
      const uint2 kvx = kvx_n, kvy = kvy_n;
      const float2 efx = efx_n, efy = efy_n;
      const float rx = __int_as_float(nAx.z), ex0 = __int_as_float(nAx.w);
      const float ex1 = nBx.x, ex2 = nBx.y;
      float ry = __int_as_float(nAy.z);
      const float ey0 = __int_as_float(nAy.w);
      const float ey1 = nBy.x, ey2 = nBy.y;

      // issue next pair's data; advance desc pipeline
      if (i + 2 < end) {
        const int cx = __builtin_amdgcn_readfirstlane(fAx.y);
        const int ex = __builtin_amdgcn_readfirstlane(fAx.x);
        const int cy = __builtin_amdgcn_readfirstlane(fAy.y);
        const int ey = __builtin_amdgcn_readfirstlane(fAy.x);
        kvx_n = kvb[(size_t)cx * 64 + t];
        kvy_n = kvb[(size_t)cy * 64 + t];
        efx_n = ef2[(size_t)ex * 64 + t];
        efy_n = ef2[(size_t)ey * 64 + t];
        nAx = fAx; nBx = fBx; nAy = fAy; nBy = fBy;
        fAx = descA[cidx(i + 4)]; fBx = descB[cidx(i + 4)];
        fAy = descA[cidx(i + 5)]; fBy = descB[cidx(i + 5)];
      }

      // unpack bf16 {k,v} pairs
      const float kx0 = bflo(kvx.x), vx0 = bfhi(kvx.x);
      const float kx1 = bflo(kvx.y), vx1 = bfhi(kvx.y);
      const float ky0 = bflo(kvy.x);
      const float ky1 = bflo(kvy.y);
      // mask duplicated odd-tail edge
      const float my = (i + 1 < end) ? 1.f : 0.f;
      const float vy0 = bfhi(kvy.x) * my, vy1 = bfhi(kvy.y) * my;
      ry *= my;

      // per-head dot: 2 local fma + xor-1 + xor-2 (head = 4 lanes)
      float p0 = q0 * kx0; p0 = fmaf(q1, kx1, p0);
      p0 += __shfl_xor(p0, 1); p0 += __shfl_xor(p0, 2);
      float p1 = q0 * ky0; p1 = fmaf(q1, ky1, p1);
      p1 += __shfl_xor(p1, 1); p1 += __shfl_xor(p1, 2);

      const float at0 = gelu_fast(p0) * rx;
      const float at1 = gelu_fast(p1) * ry;

      f0 = fmaf(vx0 * efx.x, at0, f0);
      f1 = fmaf(vx1 * efx.y, at0, f1);
      f0 = fmaf(vy0 * efy.x, at1, f0);
      f1 = fmaf(vy1 * efy.y, at1, f1);

      va0 = fmaf(vx0, ex0, fmaf(vy0, ey0, va0));
      va1 = fmaf(vx1, ex0, fmaf(vy1, ey0, va1));
      vb0 = fmaf(vx0, ex1, fmaf(vy0, ey1, vb0));
      vb1 = fmaf(vx1, ex1, fmaf(vy1, ey1, vb1));
      vc0 = fmaf(vx0, ex2, fmaf(vy0, ey2, vc0));
      vc1 = fmaf(vx1, ex2, fmaf(vy1, ey2, vc1));
    }
  }

  mfeatw[(size_t)a * 64 + t] = packbf(f0, f1);
  float* ov = outvec + (size_t)a * 384 + 2 * t;
  *reinterpret_cast<float2*>(ov)       = make_float2(va0, va1);
  *reinterpret_cast<float2*>(ov + 128) = make_float2(vb0, vb1);
  *reinterpret_cast<float2*>(ov + 256) = make_float2(vc0, vc1);
}

// ---------------------------------------------------------------------------
// K3: delta_node_feat = m_feat(bf16) @ out_wT(bf16) + out_b via MFMA,
// LDS-staged coalesced epilogue.
// ---------------------------------------------------------------------------
__global__ __launch_bounds__(256) void k_out(
    const unsigned short* __restrict__ mfeatb,
    const unsigned short* __restrict__ wTo,
    const float* __restrict__ bias, float* __restrict__ out)
{
  __shared__ float so[16][132];
  const int a0 = blockIdx.x * 16;
  const int tid = threadIdx.x;
  const int wid = tid >> 6;
  const int lane = tid & 63;
  const int lrow = lane & 15;
  const int lquad = lane >> 4;

  s16x8 afrag[4];
  #pragma unroll
  for (int ks = 0; ks < 4; ++ks)
    afrag[ks] = *reinterpret_cast<const s16x8*>(
        &mfeatb[(size_t)(a0 + lrow) * 128 + ks * 32 + lquad * 8]);

  f32x4 acc[2];
  acc[0] = (f32x4){0.f, 0.f, 0.f, 0.f};
  acc[1] = (f32x4){0.f, 0.f, 0.f, 0.f};

  #pragma unroll
  for (int t = 0; t < 2; ++t) {
    const int cg = wid * 32 + t * 16 + lrow;
    #pragma unroll
    for (int ks = 0; ks < 4; ++ks) {
      const s16x8 bf = *reinterpret_cast<const s16x8*>(
          &wTo[(size_t)cg * 128 + ks * 32 + lquad * 8]);
      acc[t] = __builtin_amdgcn_mfma_f32_16x16x32_bf16(afrag[ks], bf, acc[t], 0, 0, 0);
    }
  }

  #pragma unroll
  for (int t = 0; t < 2; ++t) {
    const int cg = wid * 32 + t * 16 + lrow;
    const float bz = bias[cg];
    #pragma unroll
    for (int r = 0; r < 4; ++r)
      so[lquad * 4 + r][cg] = acc[t][r] + bz;
  }
  __syncthreads();

  f32x4* out4 = (f32x4*)out;
  #pragma unroll
  for (int kk = 0; kk < 2; ++kk) {
    const int idx4 = tid + kk * 256;   // 0..511
    const int rowi = idx4 >> 5;
    const int c4 = idx4 & 31;
    out4[(size_t)(a0 + rowi) * 32 + c4] =
        *reinterpret_cast<const f32x4*>(&so[rowi][c4 * 4]);
  }
}

extern "C" void kernel_launch(void* const* d_in, const int* in_sizes, int n_in,
                              void* d_out, int out_size, void* d_ws, size_t ws_size,
                              hipStream_t stream) {
  const float* node_feat = (const float*)d_in[0];
  const float* edge_feat = (const float*)d_in[1];
  const float* edge_vec  = (const float*)d_in[2];
  const float* radial    = (const float*)d_in[3];
  const float* qkv_w     = (const float*)d_in[4];
  const float* qkv_b     = (const float*)d_in[5];
  const float* out_w     = (const float*)d_in[6];
  const float* out_b     = (const float*)d_in[7];
  const float* ln_g      = (const float*)d_in[8];
  const float* ln_b      = (const float*)d_in[9];
  const int*   row       = (const int*)d_in[10];
  const int*   col       = (const int*)d_in[11];

  float* out      = (float*)d_out;
  float* out_feat = out;                           // [50000][128]
  float* out_vec  = out + (size_t)NATOMS * DIM;    // [50000][3][128]

  // workspace layout (16B-aligned sections)
  unsigned* qb  = (unsigned*)d_ws;                              // 50000*64 u32 (bf16 q pairs)
  unsigned* kvb = qb + (size_t)NATOMS * 64;                     // 50000*128 u32 (bf16 {k,v})
  unsigned short* mfeatb = (unsigned short*)(kvb + (size_t)NATOMS * 128); // 50000*128 bf16
  unsigned short* wTq = mfeatb + (size_t)NATOMS * 128;          // 384*128 bf16
  unsigned short* wTo = wTq + 384 * 128;                        // 128*128 bf16
  int4* descA  = (int4*)(wTo + 128 * 128);                      // 400000 int4
  float2* descB = (float2*)(descA + NEDGES);                    // 400000 float2
  int* cnt    = (int*)(descB + NEDGES);                         // 50000
  int* base   = cnt + NATOMS;                                   // 50001
  int* cursor = base + NATOMS + 1;                              // 50000
  int* locx   = cursor + NATOMS;                                // 50000
  int* psum   = locx + NATOMS;                                  // 256
  int* poff   = psum + 256;                                     // 256

  hipMemsetAsync(cnt, 0, NATOMS * sizeof(int), stream);

  k_convert_w<<<(384 * 128 + 128 * 128) / 256, 256, 0, stream>>>(qkv_w, out_w, wTq, wTo);

  const int eb = (NEDGES + 255) / 256;
  k_hist<<<eb, 256, 0, stream>>>(row, cnt);
  k_scan1<<<SCAN_NB, 256, 0, stream>>>(cnt, locx, psum);
  k_scan2<<<1, 256, 0, stream>>>(psum, poff, base);
  k_scan3<<<SCAN_NB, 256, 0, stream>>>(locx, poff, base, cursor);
  k_scatter<<<eb, 256, 0, stream>>>(row, col, radial, edge_vec, cursor,
                                    descA, descB);

  k_ln_qkv<<<NATOMS / 16, 256, 0, stream>>>(node_feat, wTq, qkv_b, ln_g, ln_b,
                                            qb, kvb);

  k_edge_csr<<<(NATOMS + 3) / 4, 256, 0, stream>>>(
      qb, (const uint2*)kvb, (const float2*)edge_feat, descA, descB, base,
      (unsigned*)mfeatb, out_vec);

  k_out<<<NATOMS / 16, 256, 0, stream>>>(mfeatb, wTo, out_b, out_feat);
}